// Round 1
// baseline (30727.484 us; speedup 1.0000x reference)
//
#include <hip/hip_runtime.h>

// NodeDenoisingADMM: N=20000, FEAT=64, K=4, NNZ=320000, NU=2.0, GAMMA=1.0, J=3
// 14 scan iterations (thres_iter=15 - 1), output = final Uk (N, FEAT) fp32.
//
// Per-iteration (GAMMA=1):
//   Z   = soft(S + Y, nu_k * d)        S := W_k @ U  (carried from prev iter)
//   v   = Y - Z                        (stored in-place over S)
//   WTV = sum_k W_k @ v_k
//   U   = (num_f - WTV) / denom
//   S   = W_k @ U                      (reused next iter; skipped last iter)
//   Y  += S - Z                        (skipped last iter)

constexpr int N_    = 20000;
constexpr int FEAT_ = 64;
constexpr int K_    = 4;
constexpr int NNZ_  = 320000;
constexpr int NF    = N_ * FEAT_;     // 1,280,000
constexpr int KNF   = K_ * NF;        // 5,120,000
constexpr int NEDGE = K_ * NNZ_;      // 1,280,000
constexpr int NITER = 14;             // thres_iter(15) - 1
constexpr int BLK   = 256;

__constant__ float c_nu[4] = {0.0f, 2.0f, 0.5f, 0.125f};  // [0] + NU/4^i

__device__ __forceinline__ float softf(float x, float t) {
    float a = fabsf(x) - t;
    a = a > 0.0f ? a : 0.0f;
    return copysignf(a, x);
}

// num_f = d * mask^2 * F ; denom = d*mask^2 + 1
__global__ __launch_bounds__(BLK) void precompute_kernel(
    const float* __restrict__ F, const float* __restrict__ d,
    const float* __restrict__ mask, float* __restrict__ num_f,
    float* __restrict__ denom) {
    int i = blockIdx.x * BLK + threadIdx.x;           // over NF/4 float4s
    if (i >= NF / 4) return;
    int n = i / (FEAT_ / 4);
    float dm = d[n] * mask[n] * mask[n];
    float4 f = ((const float4*)F)[i];
    float4 o;
    o.x = dm * f.x; o.y = dm * f.y; o.z = dm * f.z; o.w = dm * f.w;
    ((float4*)num_f)[i] = o;
    if ((i & (FEAT_ / 4 - 1)) == 0) denom[n] = dm + 1.0f;
}

// Z = soft(S + Y, nu_k*d[n]); V(=S in-place) = Y - Z
__global__ __launch_bounds__(BLK) void ewise_zv_kernel(
    const float* __restrict__ S, const float* __restrict__ Y,
    const float* __restrict__ d, float* __restrict__ Z,
    float* __restrict__ V) {
    int i = blockIdx.x * BLK + threadIdx.x;           // over KNF/4
    if (i >= KNF / 4) return;
    int ng = i / (FEAT_ / 4);                         // k*N + n
    int k = ng / N_;
    int n = ng - k * N_;
    float t = c_nu[k] * d[n];
    float4 s = ((const float4*)S)[i];
    float4 y = ((const float4*)Y)[i];
    float4 z, v;
    z.x = softf(s.x + y.x, t); v.x = y.x - z.x;
    z.y = softf(s.y + y.y, t); v.y = y.y - z.y;
    z.z = softf(s.z + y.z, t); v.z = y.z - z.z;
    z.w = softf(s.w + y.w, t); v.w = y.w - z.w;
    ((float4*)Z)[i] = z;
    ((float4*)V)[i] = v;
}

// U = (num_f - WTV) / denom[n]
__global__ __launch_bounds__(BLK) void ewise_u_kernel(
    const float* __restrict__ num_f, const float* __restrict__ WTV,
    const float* __restrict__ denom, float* __restrict__ U) {
    int i = blockIdx.x * BLK + threadIdx.x;           // over NF/4
    if (i >= NF / 4) return;
    int n = i / (FEAT_ / 4);
    float r = 1.0f / denom[n];
    float4 a = ((const float4*)num_f)[i];
    float4 b = ((const float4*)WTV)[i];
    float4 o;
    o.x = (a.x - b.x) * r; o.y = (a.y - b.y) * r;
    o.z = (a.z - b.z) * r; o.w = (a.w - b.w) * r;
    ((float4*)U)[i] = o;
}

// Y += S - Z
__global__ __launch_bounds__(BLK) void ewise_y_kernel(
    float* __restrict__ Y, const float* __restrict__ S,
    const float* __restrict__ Z) {
    int i = blockIdx.x * BLK + threadIdx.x;           // over KNF/4
    if (i >= KNF / 4) return;
    float4 y = ((const float4*)Y)[i];
    float4 s = ((const float4*)S)[i];
    float4 z = ((const float4*)Z)[i];
    y.x += s.x - z.x; y.y += s.y - z.y;
    y.z += s.z - z.z; y.w += s.w - z.w;
    ((float4*)Y)[i] = y;
}

// Generic atomic spmm over all K graphs:
//   out[k*out_stride + row*FEAT + :] += val * X[k*x_stride + col*FEAT + :]
// x_stride=0  -> shared X (spmm_shared);  out_stride=0 -> summed output (WTV).
// One thread per (edge, feature-quad): 16 threads/edge, float4 gather.
__global__ __launch_bounds__(BLK) void spmm_atomic_kernel(
    const int* __restrict__ rows, const int* __restrict__ cols,
    const float* __restrict__ vals, const float* __restrict__ X,
    float* __restrict__ out, int x_stride, int out_stride) {
    int t = blockIdx.x * BLK + threadIdx.x;
    int eg = t >> 4;                                  // global edge index
    int q  = t & 15;                                  // feature quad
    if (eg >= NEDGE) return;
    int k   = eg / NNZ_;
    int row = rows[eg];
    int col = cols[eg];
    float val = vals[eg];
    const float4* xr = (const float4*)(X + (long)k * x_stride + col * FEAT_);
    float4 xv = xr[q];
    float* o = out + (long)k * out_stride + row * FEAT_ + q * 4;
    atomicAdd(o + 0, val * xv.x);
    atomicAdd(o + 1, val * xv.y);
    atomicAdd(o + 2, val * xv.z);
    atomicAdd(o + 3, val * xv.w);
}

extern "C" void kernel_launch(void* const* d_in, const int* in_sizes, int n_in,
                              void* d_out, int out_size, void* d_ws, size_t ws_size,
                              hipStream_t stream) {
    const float* F      = (const float*)d_in[0];
    const int*   w_rows = (const int*)d_in[1];
    const int*   w_cols = (const int*)d_in[2];
    const float* w_vals = (const float*)d_in[3];
    const float* d      = (const float*)d_in[4];
    const float* mask   = (const float*)d_in[5];
    float* U = (float*)d_out;                         // Uk lives in d_out

    float* S     = (float*)d_ws;                      // KNF  (doubles as v)
    float* Z     = S + KNF;                           // KNF
    float* Y     = Z + KNF;                           // KNF
    float* WTV   = Y + KNF;                           // NF
    float* num_f = WTV + NF;                          // NF
    float* denom = num_f + NF;                        // N
    // total: 3*KNF + 2*NF + N floats ~= 71.9 MB

    const int gEdge = (NEDGE * 16) / BLK;             // 80000 blocks, exact
    const int gKNF  = (KNF / 4) / BLK;                // 5000 blocks, exact
    const int gNF   = (NF / 4) / BLK;                 // 1250 blocks, exact

    hipMemsetAsync(Y, 0, (size_t)KNF * 4, stream);
    hipMemsetAsync(S, 0, (size_t)KNF * 4, stream);
    precompute_kernel<<<gNF, BLK, 0, stream>>>(F, d, mask, num_f, denom);
    // S = W_k @ F  (initial U = F)
    spmm_atomic_kernel<<<gEdge, BLK, 0, stream>>>(w_rows, w_cols, w_vals,
                                                  F, S, 0, NF);

    for (int it = 0; it < NITER; ++it) {
        ewise_zv_kernel<<<gKNF, BLK, 0, stream>>>(S, Y, d, Z, S);
        hipMemsetAsync(WTV, 0, (size_t)NF * 4, stream);
        // WTV = sum_k W_k @ v_k   (v lives in S)
        spmm_atomic_kernel<<<gEdge, BLK, 0, stream>>>(w_rows, w_cols, w_vals,
                                                      S, WTV, NF, 0);
        ewise_u_kernel<<<gNF, BLK, 0, stream>>>(num_f, WTV, denom, U);
        if (it < NITER - 1) {
            hipMemsetAsync(S, 0, (size_t)KNF * 4, stream);
            // S = W_k @ U  (reused by next iteration's Z)
            spmm_atomic_kernel<<<gEdge, BLK, 0, stream>>>(w_rows, w_cols, w_vals,
                                                          U, S, 0, NF);
            ewise_y_kernel<<<gKNF, BLK, 0, stream>>>(Y, S, Z);
        }
    }
}

// Round 2
// 2573.029 us; speedup vs baseline: 11.9421x; 11.9421x over previous
//
#include <hip/hip_runtime.h>

// NodeDenoisingADMM: N=20000, FEAT=64, K=4, NNZ=320000, NU=2.0, GAMMA=1.0, J=3
// 14 scan iterations, output = final U (N,FEAT) fp32.
//
// Algebraic reduction (GAMMA=1): the whole carried state is v alone.
//   S_t = W_k @ U_t          (wave-per-(k,row) CSR gather)
//   Y_t = S_t + v_{t-1}      (Y_t = Y_{t-1} + S_t - Z_{t-1}, v = Y - Z)
//   Z_t = soft(S_t + Y_t, nu_k * d)
//   v_t = Y_t - Z_t
//   U_{t+1} = (dm*F - sum_k W_k v_k) / (dm + 1),  dm = d * mask^2
// CSR (counting sort by row, per graph) built per call -> no atomics in loop.

constexpr int N_    = 20000;
constexpr int FEAT_ = 64;
constexpr int K_    = 4;
constexpr int NNZ_  = 320000;
constexpr int NF    = N_ * FEAT_;     // 1,280,000
constexpr int KN    = K_ * N_;        // 80,000 (csr rows)
constexpr int NEDGE = K_ * NNZ_;      // 1,280,000
constexpr int NITER = 14;
constexpr int BLK   = 256;

__constant__ float c_nu[4] = {0.0f, 2.0f, 0.5f, 0.125f};  // [0] + NU/4^i

__device__ __forceinline__ float softf(float x, float t) {
    float a = fabsf(x) - t;
    a = a > 0.0f ? a : 0.0f;
    return copysignf(a, x);
}

// dm[n] = d[n] * mask[n]^2
__global__ __launch_bounds__(BLK) void precompute_kernel(
    const float* __restrict__ d, const float* __restrict__ mask,
    float* __restrict__ dm) {
    int n = blockIdx.x * BLK + threadIdx.x;
    if (n >= N_) return;
    dm[n] = d[n] * mask[n] * mask[n];
}

// cnt[k*N + rows[e]]++  (cnt lives in `cursor`)
__global__ __launch_bounds__(BLK) void hist_kernel(
    const int* __restrict__ rows, int* __restrict__ cnt) {
    int e = blockIdx.x * BLK + threadIdx.x;
    if (e >= NEDGE) return;
    int k = e / NNZ_;
    atomicAdd(&cnt[k * N_ + rows[e]], 1);
}

// single-block exclusive scan of cnt[KN] -> offs[KN+1]; also cnt <- prefix
// (so it can serve as the scatter cursor).
__global__ __launch_bounds__(1024) void scan_kernel(
    int* __restrict__ cnt, int* __restrict__ offs) {
    __shared__ int buf[1024];
    __shared__ int s_carry;
    int tid = threadIdx.x;
    if (tid == 0) s_carry = 0;
    __syncthreads();
    for (int base = 0; base < KN; base += 1024) {
        int i = base + tid;
        int x = (i < KN) ? cnt[i] : 0;
        buf[tid] = x;
        __syncthreads();
        for (int off = 1; off < 1024; off <<= 1) {
            int t = (tid >= off) ? buf[tid - off] : 0;
            __syncthreads();
            buf[tid] += t;
            __syncthreads();
        }
        int incl = buf[tid];
        int run  = s_carry;
        if (i < KN) {
            int excl = run + incl - x;
            offs[i] = excl;
            cnt[i]  = excl;
        }
        __syncthreads();
        if (tid == 1023) s_carry = run + incl;
        __syncthreads();
    }
    if (tid == 0) offs[KN] = s_carry;
}

// scatter edges into CSR order: pos = cursor[k*N+row]++; ccol/cval[pos] = ...
__global__ __launch_bounds__(BLK) void scatter_kernel(
    const int* __restrict__ rows, const int* __restrict__ cols,
    const float* __restrict__ vals, int* __restrict__ cursor,
    int* __restrict__ ccol, float* __restrict__ cval) {
    int e = blockIdx.x * BLK + threadIdx.x;
    if (e >= NEDGE) return;
    int k = e / NNZ_;
    int pos = atomicAdd(&cursor[k * N_ + rows[e]], 1);
    ccol[pos] = cols[e];
    cval[pos] = vals[e];
}

// wave-per-(k,row): acc = (W_k @ X)[row, lane]; then fused Y/Z/v update.
// FIRST: Y=0 path (initial U = F, Y_0 = 0).
template <bool FIRST>
__global__ __launch_bounds__(BLK) void spmm_fused_kernel(
    const int* __restrict__ offs, const int* __restrict__ ccol,
    const float* __restrict__ cval, const float* __restrict__ X,
    const float* __restrict__ d, float* __restrict__ V) {
    int w    = (blockIdx.x * BLK + threadIdx.x) >> 6;  // k*N + row
    int lane = threadIdx.x & 63;
    if (w >= KN) return;
    int k   = w / N_;
    int row = w - k * N_;
    int beg = __builtin_amdgcn_readfirstlane(offs[w]);
    int end = __builtin_amdgcn_readfirstlane(offs[w + 1]);
    float acc = 0.0f;
    for (int e = beg; e < end; ++e) {
        int   c = ccol[e];
        float v = cval[e];
        acc += v * X[c * FEAT_ + lane];
    }
    int   idx = w * FEAT_ + lane;
    float thr = c_nu[k] * d[row];
    float y   = FIRST ? 0.0f : (acc + V[idx]);   // Y_t = S_t + v_{t-1}
    float z   = softf(acc + y, thr);             // Z_t = soft(S_t + Y_t)
    V[idx]    = y - z;                           // v_t
}

// wave-per-row: acc = sum_k (W_k @ v_k)[row, lane]; U = (dm*F - acc)/(dm+1)
__global__ __launch_bounds__(BLK) void wtv_u_kernel(
    const int* __restrict__ offs, const int* __restrict__ ccol,
    const float* __restrict__ cval, const float* __restrict__ V,
    const float* __restrict__ F, const float* __restrict__ dm,
    float* __restrict__ U) {
    int w    = (blockIdx.x * BLK + threadIdx.x) >> 6;  // row
    int lane = threadIdx.x & 63;
    if (w >= N_) return;
    float acc = 0.0f;
    for (int k = 0; k < K_; ++k) {
        int rw  = k * N_ + w;
        int beg = __builtin_amdgcn_readfirstlane(offs[rw]);
        int end = __builtin_amdgcn_readfirstlane(offs[rw + 1]);
        const float* Vk = V + (size_t)k * NF;
        for (int e = beg; e < end; ++e)
            acc += cval[e] * Vk[ccol[e] * FEAT_ + lane];
    }
    int   idx = w * FEAT_ + lane;
    float dmv = dm[w];
    U[idx] = (dmv * F[idx] - acc) / (dmv + 1.0f);
}

extern "C" void kernel_launch(void* const* d_in, const int* in_sizes, int n_in,
                              void* d_out, int out_size, void* d_ws, size_t ws_size,
                              hipStream_t stream) {
    const float* F      = (const float*)d_in[0];
    const int*   w_rows = (const int*)d_in[1];
    const int*   w_cols = (const int*)d_in[2];
    const float* w_vals = (const float*)d_in[3];
    const float* d      = (const float*)d_in[4];
    const float* mask   = (const float*)d_in[5];
    float* U = (float*)d_out;

    // workspace layout (4-byte units): total ~31.4 MB
    float* V      = (float*)d_ws;          // KN*FEAT = 5,120,000
    float* dm     = V + (size_t)KN * FEAT_;      // N
    int*   offs   = (int*)(dm + N_);             // KN+1
    int*   cursor = offs + KN + 1;               // KN
    int*   ccol   = cursor + KN;                 // NEDGE
    float* cval   = (float*)(ccol + NEDGE);      // NEDGE

    const int gEdge = NEDGE / BLK;               // 5000, exact
    const int gKNw  = (KN * 64) / BLK;           // 20000 blocks (wave per csr-row)
    const int gNw   = (N_ * 64) / BLK;           // 5000 blocks (wave per row)
    const int gN    = (N_ + BLK - 1) / BLK;

    // ---- CSR build (per call; inputs re-poisoned each replay) ----
    hipMemsetAsync(cursor, 0, (size_t)KN * 4, stream);
    precompute_kernel<<<gN, BLK, 0, stream>>>(d, mask, dm);
    hist_kernel<<<gEdge, BLK, 0, stream>>>(w_rows, cursor);
    scan_kernel<<<1, 1024, 0, stream>>>(cursor, offs);
    scatter_kernel<<<gEdge, BLK, 0, stream>>>(w_rows, w_cols, w_vals,
                                              cursor, ccol, cval);

    // ---- iteration 1: U = F, Y = 0 -> v_0 ----
    spmm_fused_kernel<true><<<gKNw, BLK, 0, stream>>>(offs, ccol, cval, F, d, V);

    for (int it = 0; it < NITER; ++it) {
        wtv_u_kernel<<<gNw, BLK, 0, stream>>>(offs, ccol, cval, V, F, dm, U);
        if (it < NITER - 1)
            spmm_fused_kernel<false><<<gKNw, BLK, 0, stream>>>(offs, ccol, cval,
                                                               U, d, V);
    }
}

// Round 3
// 1600.126 us; speedup vs baseline: 19.2032x; 1.6080x over previous
//
#include <hip/hip_runtime.h>

// NodeDenoisingADMM: N=20000, FEAT=64, K=4, NNZ=320000, NU=2.0, GAMMA=1.0, J=3
// 14 scan iterations, output = final U (N,FEAT) fp32.
//
// State reduction (GAMMA=1): carried state is v alone.
//   S_t = W_k @ U_t ; Y_t = S_t + v_{t-1} ; Z_t = soft(S_t + Y_t, nu_k d)
//   v_t = Y_t - Z_t ; U_{t+1} = (dm*F - sum_k W_k v_k)/(dm+1), dm = d*mask^2
//
// spmm: wave per CSR row, 4 edges per iteration, float4 gathers
// (lane = 16*sub_edge + quad), shfl_xor(16,32) butterfly to reduce subs.

constexpr int N_    = 20000;
constexpr int FEAT_ = 64;
constexpr int K_    = 4;
constexpr int NNZ_  = 320000;
constexpr int NF    = N_ * FEAT_;     // 1,280,000
constexpr int KN    = K_ * N_;        // 80,000 CSR rows
constexpr int NEDGE = K_ * NNZ_;      // 1,280,000
constexpr int NITER = 14;
constexpr int BLK   = 256;
constexpr int NSB   = (KN + 255) / 256;  // 313 scan blocks

__constant__ float c_nu[4] = {0.0f, 2.0f, 0.5f, 0.125f};

__device__ __forceinline__ float softf(float x, float t) {
    float a = fabsf(x) - t;
    a = a > 0.0f ? a : 0.0f;
    return copysignf(a, x);
}

// ---------------- CSR build ----------------

__global__ __launch_bounds__(BLK) void precompute_kernel(
    const float* __restrict__ d, const float* __restrict__ mask,
    float* __restrict__ dm) {
    int n = blockIdx.x * BLK + threadIdx.x;
    if (n >= N_) return;
    dm[n] = d[n] * mask[n] * mask[n];
}

__global__ __launch_bounds__(BLK) void hist_kernel(
    const int* __restrict__ rows, int* __restrict__ cnt) {
    int e = blockIdx.x * BLK + threadIdx.x;
    if (e >= NEDGE) return;
    int k = e / NNZ_;
    atomicAdd(&cnt[k * N_ + rows[e]], 1);
}

// block-local exclusive scan (256/block) + block sums
__global__ __launch_bounds__(256) void scan1_kernel(
    const int* __restrict__ cnt, int* __restrict__ loc,
    int* __restrict__ bsum) {
    int i = blockIdx.x * 256 + threadIdx.x;
    int x = (i < KN) ? cnt[i] : 0;
    int lane = threadIdx.x & 63, wid = threadIdx.x >> 6;
    int v = x;
    #pragma unroll
    for (int off = 1; off < 64; off <<= 1) {
        int t = __shfl_up(v, off, 64);
        if (lane >= off) v += t;
    }
    __shared__ int ws[4];
    if (lane == 63) ws[wid] = v;
    __syncthreads();
    int add = 0;
    for (int u = 0; u < wid; ++u) add += ws[u];
    v += add;
    if (i < KN) loc[i] = v - x;
    if (threadIdx.x == 255) bsum[blockIdx.x] = v;
}

// single-block exclusive scan of the 313 block sums
__global__ __launch_bounds__(512) void scan2_kernel(int* __restrict__ bsum) {
    int tid = threadIdx.x;
    int x = (tid < NSB) ? bsum[tid] : 0;
    int lane = tid & 63, wid = tid >> 6;
    int v = x;
    #pragma unroll
    for (int off = 1; off < 64; off <<= 1) {
        int t = __shfl_up(v, off, 64);
        if (lane >= off) v += t;
    }
    __shared__ int ws[8];
    if (lane == 63) ws[wid] = v;
    __syncthreads();
    int add = 0;
    for (int u = 0; u < wid; ++u) add += ws[u];
    v += add;
    if (tid < NSB) bsum[tid] = v - x;
}

// offs/cursor = loc + bsum[block]; offs[KN] = NEDGE (total is exact)
__global__ __launch_bounds__(256) void scan3_kernel(
    const int* __restrict__ loc, const int* __restrict__ bsum,
    int* __restrict__ offs, int* __restrict__ cursor) {
    int i = blockIdx.x * 256 + threadIdx.x;
    if (i < KN) {
        int v = loc[i] + bsum[blockIdx.x];
        offs[i] = v;
        cursor[i] = v;
    }
    if (i == 0) offs[KN] = NEDGE;
}

__global__ __launch_bounds__(BLK) void scatter_kernel(
    const int* __restrict__ rows, const int* __restrict__ cols,
    const float* __restrict__ vals, int* __restrict__ cursor,
    int* __restrict__ ccol, float* __restrict__ cval) {
    int e = blockIdx.x * BLK + threadIdx.x;
    if (e >= NEDGE) return;
    int k = e / NNZ_;
    int pos = atomicAdd(&cursor[k * N_ + rows[e]], 1);
    ccol[pos] = cols[e];
    cval[pos] = vals[e];
}

// ---------------- iteration kernels ----------------

__device__ __forceinline__ void row_accum(
    const int* __restrict__ ccol, const float* __restrict__ cval,
    const float4* __restrict__ X4, int beg, int end, int sub, int q,
    float4& acc) {
    int nIter = (end - beg + 3) >> 2;       // wave-uniform
    int e = beg + sub;
    for (int it = 0; it < nIter; ++it, e += 4) {
        int c = 0; float v = 0.0f;
        if (e < end) { c = ccol[e]; v = cval[e]; }
        float4 x = X4[c * (FEAT_ / 4) + q];
        acc.x += v * x.x; acc.y += v * x.y;
        acc.z += v * x.z; acc.w += v * x.w;
    }
}

__device__ __forceinline__ void butterfly4(float4& a) {
    #pragma unroll
    for (int m = 16; m <= 32; m <<= 1) {
        a.x += __shfl_xor(a.x, m, 64);
        a.y += __shfl_xor(a.y, m, 64);
        a.z += __shfl_xor(a.z, m, 64);
        a.w += __shfl_xor(a.w, m, 64);
    }
}

// wave per (k,row): acc = (W_k @ X)[row]; fused v-update. FIRST: Y=0, X=F.
template <bool FIRST>
__global__ __launch_bounds__(BLK) void spmm_fused_kernel(
    const int* __restrict__ offs, const int* __restrict__ ccol,
    const float* __restrict__ cval, const float* __restrict__ X,
    const float* __restrict__ d, float* __restrict__ V) {
    int w    = (blockIdx.x * BLK + threadIdx.x) >> 6;  // k*N + row
    int lane = threadIdx.x & 63;
    int sub  = lane >> 4, q = lane & 15;
    if (w >= KN) return;
    int k   = w / N_;
    int row = w - k * N_;
    int beg = __builtin_amdgcn_readfirstlane(offs[w]);
    int end = __builtin_amdgcn_readfirstlane(offs[w + 1]);
    float4 acc = {0.f, 0.f, 0.f, 0.f};
    row_accum(ccol, cval, (const float4*)X, beg, end, sub, q, acc);
    butterfly4(acc);                         // all lanes now hold row sums
    if (sub == 0) {
        int idx4 = w * (FEAT_ / 4) + q;
        float thr = c_nu[k] * d[row];
        float4* V4 = (float4*)V;
        float4 y;
        if (FIRST) {
            y = make_float4(0.f, 0.f, 0.f, 0.f);
        } else {
            float4 vp = V4[idx4];            // v_{t-1}
            y.x = acc.x + vp.x; y.y = acc.y + vp.y;
            y.z = acc.z + vp.z; y.w = acc.w + vp.w;
        }
        float4 o;
        o.x = y.x - softf(acc.x + y.x, thr);
        o.y = y.y - softf(acc.y + y.y, thr);
        o.z = y.z - softf(acc.z + y.z, thr);
        o.w = y.w - softf(acc.w + y.w, thr);
        V4[idx4] = o;                        // v_t
    }
}

// wave per row: acc = sum_k (W_k @ v_k)[row]; U = (dm*F - acc)/(dm+1)
__global__ __launch_bounds__(BLK) void wtv_u_kernel(
    const int* __restrict__ offs, const int* __restrict__ ccol,
    const float* __restrict__ cval, const float* __restrict__ V,
    const float* __restrict__ F, const float* __restrict__ dm,
    float* __restrict__ U) {
    int w    = (blockIdx.x * BLK + threadIdx.x) >> 6;  // row
    int lane = threadIdx.x & 63;
    int sub  = lane >> 4, q = lane & 15;
    if (w >= N_) return;
    float4 acc = {0.f, 0.f, 0.f, 0.f};
    #pragma unroll
    for (int k = 0; k < K_; ++k) {
        int rw  = k * N_ + w;
        int beg = __builtin_amdgcn_readfirstlane(offs[rw]);
        int end = __builtin_amdgcn_readfirstlane(offs[rw + 1]);
        row_accum(ccol, cval, (const float4*)(V + (size_t)k * NF),
                  beg, end, sub, q, acc);
    }
    butterfly4(acc);
    if (sub == 0) {
        int idx4 = w * (FEAT_ / 4) + q;
        float dmv = dm[w];
        float r = 1.0f / (dmv + 1.0f);
        float4 f = ((const float4*)F)[idx4];
        float4 o;
        o.x = (dmv * f.x - acc.x) * r; o.y = (dmv * f.y - acc.y) * r;
        o.z = (dmv * f.z - acc.z) * r; o.w = (dmv * f.w - acc.w) * r;
        ((float4*)U)[idx4] = o;
    }
}

extern "C" void kernel_launch(void* const* d_in, const int* in_sizes, int n_in,
                              void* d_out, int out_size, void* d_ws, size_t ws_size,
                              hipStream_t stream) {
    const float* F      = (const float*)d_in[0];
    const int*   w_rows = (const int*)d_in[1];
    const int*   w_cols = (const int*)d_in[2];
    const float* w_vals = (const float*)d_in[3];
    const float* d      = (const float*)d_in[4];
    const float* mask   = (const float*)d_in[5];
    float* U = (float*)d_out;

    // workspace layout (~32.5 MB)
    float* V      = (float*)d_ws;                 // 5,120,000 f
    float* dm     = V + (size_t)KN * FEAT_ / K_ * K_;  // = V + 5,120,000
    int*   cnt    = (int*)(dm + N_);              // KN
    int*   loc    = cnt + KN;                     // KN
    int*   bsum   = loc + KN;                     // NSB (pad 512)
    int*   offs   = bsum + 512;                   // KN+1
    int*   cursor = offs + KN + 1;                // KN
    int*   ccol   = cursor + KN;                  // NEDGE
    float* cval   = (float*)(ccol + NEDGE);       // NEDGE

    const int gEdge = NEDGE / BLK;                // 5000
    const int gKNw  = (KN * 64) / BLK;            // 20000 (wave per csr row)
    const int gNw   = (N_ * 64) / BLK;            // 5000  (wave per node row)
    const int gN    = (N_ + BLK - 1) / BLK;

    // ---- CSR build ----
    hipMemsetAsync(cnt, 0, (size_t)KN * 4, stream);
    precompute_kernel<<<gN, BLK, 0, stream>>>(d, mask, dm);
    hist_kernel<<<gEdge, BLK, 0, stream>>>(w_rows, cnt);
    scan1_kernel<<<NSB, 256, 0, stream>>>(cnt, loc, bsum);
    scan2_kernel<<<1, 512, 0, stream>>>(bsum);
    scan3_kernel<<<NSB, 256, 0, stream>>>(loc, bsum, offs, cursor);
    scatter_kernel<<<gEdge, BLK, 0, stream>>>(w_rows, w_cols, w_vals,
                                              cursor, ccol, cval);

    // ---- iterations ----
    spmm_fused_kernel<true><<<gKNw, BLK, 0, stream>>>(offs, ccol, cval, F, d, V);
    for (int it = 0; it < NITER; ++it) {
        wtv_u_kernel<<<gNw, BLK, 0, stream>>>(offs, ccol, cval, V, F, dm, U);
        if (it < NITER - 1)
            spmm_fused_kernel<false><<<gKNw, BLK, 0, stream>>>(offs, ccol, cval,
                                                               U, d, V);
    }
}

// Round 4
// 1370.046 us; speedup vs baseline: 22.4281x; 1.1679x over previous
//
#include <hip/hip_runtime.h>

// NodeDenoisingADMM: N=20000, FEAT=64, K=4, NNZ=320000, NU=2.0, GAMMA=1.0, J=3
// 14 scan iterations, output = final U (N,FEAT) fp32.
//
// State reduction (GAMMA=1): carried state is v alone.
//   S_t = W_k @ U_t ; Y_t = S_t + v_{t-1} ; Z_t = soft(S_t + Y_t, nu_k d)
//   v_t = Y_t - Z_t ; U_{t+1} = (dm*F - sum_k W_k v_k)/(dm+1), dm = d*mask^2
//
// spmm: wave per CSR row. Edge meta (ccol/cval) for a 64-edge chunk is loaded
// with ONE coalesced lane-parallel load, then broadcast per sub-edge via
// __shfl — removes the serial meta-load from the gather dependency chain.
// lane = 16*sub_edge + quad; each sub-edge gathers a 256B X row as float4s;
// shfl_xor(16,32) butterfly reduces the 4 sub-accumulators.

constexpr int N_    = 20000;
constexpr int FEAT_ = 64;
constexpr int K_    = 4;
constexpr int NNZ_  = 320000;
constexpr int NF    = N_ * FEAT_;     // 1,280,000
constexpr int KN    = K_ * N_;        // 80,000 CSR rows
constexpr int NEDGE = K_ * NNZ_;      // 1,280,000
constexpr int NITER = 14;
constexpr int BLK   = 256;
constexpr int NSB   = (KN + 255) / 256;  // 313 scan blocks

__constant__ float c_nu[4] = {0.0f, 2.0f, 0.5f, 0.125f};

__device__ __forceinline__ float softf(float x, float t) {
    float a = fabsf(x) - t;
    a = a > 0.0f ? a : 0.0f;
    return copysignf(a, x);
}

// ---------------- CSR build ----------------

__global__ __launch_bounds__(BLK) void precompute_kernel(
    const float* __restrict__ d, const float* __restrict__ mask,
    float* __restrict__ dm) {
    int n = blockIdx.x * BLK + threadIdx.x;
    if (n >= N_) return;
    dm[n] = d[n] * mask[n] * mask[n];
}

__global__ __launch_bounds__(BLK) void hist_kernel(
    const int* __restrict__ rows, int* __restrict__ cnt) {
    int e = blockIdx.x * BLK + threadIdx.x;
    if (e >= NEDGE) return;
    int k = e / NNZ_;
    atomicAdd(&cnt[k * N_ + rows[e]], 1);
}

// block-local exclusive scan (256/block) + block sums
__global__ __launch_bounds__(256) void scan1_kernel(
    const int* __restrict__ cnt, int* __restrict__ loc,
    int* __restrict__ bsum) {
    int i = blockIdx.x * 256 + threadIdx.x;
    int x = (i < KN) ? cnt[i] : 0;
    int lane = threadIdx.x & 63, wid = threadIdx.x >> 6;
    int v = x;
    #pragma unroll
    for (int off = 1; off < 64; off <<= 1) {
        int t = __shfl_up(v, off, 64);
        if (lane >= off) v += t;
    }
    __shared__ int ws[4];
    if (lane == 63) ws[wid] = v;
    __syncthreads();
    int add = 0;
    for (int u = 0; u < wid; ++u) add += ws[u];
    v += add;
    if (i < KN) loc[i] = v - x;
    if (threadIdx.x == 255) bsum[blockIdx.x] = v;
}

// single-block exclusive scan of the 313 block sums
__global__ __launch_bounds__(512) void scan2_kernel(int* __restrict__ bsum) {
    int tid = threadIdx.x;
    int x = (tid < NSB) ? bsum[tid] : 0;
    int lane = tid & 63, wid = tid >> 6;
    int v = x;
    #pragma unroll
    for (int off = 1; off < 64; off <<= 1) {
        int t = __shfl_up(v, off, 64);
        if (lane >= off) v += t;
    }
    __shared__ int ws[8];
    if (lane == 63) ws[wid] = v;
    __syncthreads();
    int add = 0;
    for (int u = 0; u < wid; ++u) add += ws[u];
    v += add;
    if (tid < NSB) bsum[tid] = v - x;
}

// offs/cursor = loc + bsum[block]; offs[KN] = NEDGE
__global__ __launch_bounds__(256) void scan3_kernel(
    const int* __restrict__ loc, const int* __restrict__ bsum,
    int* __restrict__ offs, int* __restrict__ cursor) {
    int i = blockIdx.x * 256 + threadIdx.x;
    if (i < KN) {
        int v = loc[i] + bsum[blockIdx.x];
        offs[i] = v;
        cursor[i] = v;
    }
    if (i == 0) offs[KN] = NEDGE;
}

// scatter only the permutation (4B random writes instead of 8B)
__global__ __launch_bounds__(BLK) void scatter_perm_kernel(
    const int* __restrict__ rows, int* __restrict__ cursor,
    int* __restrict__ perm) {
    int e = blockIdx.x * BLK + threadIdx.x;
    if (e >= NEDGE) return;
    int k = e / NNZ_;
    int pos = atomicAdd(&cursor[k * N_ + rows[e]], 1);
    perm[pos] = e;
}

// coalesced-write build: ccol/cval[pos] = cols/vals[perm[pos]]
__global__ __launch_bounds__(BLK) void build_kernel(
    const int* __restrict__ perm, const int* __restrict__ cols,
    const float* __restrict__ vals, int* __restrict__ ccol,
    float* __restrict__ cval) {
    int pos = blockIdx.x * BLK + threadIdx.x;
    if (pos >= NEDGE) return;
    int e = perm[pos];
    ccol[pos] = cols[e];
    cval[pos] = vals[e];
}

// ---------------- iteration kernels ----------------

// Accumulate one CSR row into acc (float4 per lane, sub-edge parallel).
// Meta for up to 64 edges is loaded lane-parallel once per chunk, then
// broadcast via __shfl — only the X gather remains a loop-carried load.
__device__ __forceinline__ void row_accum(
    const int* __restrict__ ccol, const float* __restrict__ cval,
    const float4* __restrict__ X4, int beg, int end, int lane, int sub,
    int q, float4& acc) {
    for (int base = beg; base < end; base += 64) {
        int n = end - base;              // wave-uniform
        if (n > 64) n = 64;
        int   c_l = 0;
        float v_l = 0.0f;
        if (lane < n) {
            c_l = ccol[base + lane];
            v_l = cval[base + lane];
        }
        int iters = (n + 3) >> 2;
        #pragma unroll 2
        for (int it = 0; it < iters; ++it) {
            int j = 4 * it + sub;        // j < 64; lanes >= n hold c=0,v=0
            int   c = __shfl(c_l, j, 64);
            float v = __shfl(v_l, j, 64);
            float4 x = X4[c * (FEAT_ / 4) + q];
            acc.x += v * x.x; acc.y += v * x.y;
            acc.z += v * x.z; acc.w += v * x.w;
        }
    }
}

__device__ __forceinline__ void butterfly4(float4& a) {
    #pragma unroll
    for (int m = 16; m <= 32; m <<= 1) {
        a.x += __shfl_xor(a.x, m, 64);
        a.y += __shfl_xor(a.y, m, 64);
        a.z += __shfl_xor(a.z, m, 64);
        a.w += __shfl_xor(a.w, m, 64);
    }
}

// wave per (k,row): acc = (W_k @ X)[row]; fused v-update. FIRST: Y=0, X=F.
template <bool FIRST>
__global__ __launch_bounds__(BLK) void spmm_fused_kernel(
    const int* __restrict__ offs, const int* __restrict__ ccol,
    const float* __restrict__ cval, const float* __restrict__ X,
    const float* __restrict__ d, float* __restrict__ V) {
    int w    = (blockIdx.x * BLK + threadIdx.x) >> 6;  // k*N + row
    int lane = threadIdx.x & 63;
    int sub  = lane >> 4, q = lane & 15;
    if (w >= KN) return;
    int k   = w / N_;
    int row = w - k * N_;
    int beg = __builtin_amdgcn_readfirstlane(offs[w]);
    int end = __builtin_amdgcn_readfirstlane(offs[w + 1]);
    float4 acc = {0.f, 0.f, 0.f, 0.f};
    row_accum(ccol, cval, (const float4*)X, beg, end, lane, sub, q, acc);
    butterfly4(acc);                         // all lanes hold row sums
    if (sub == 0) {
        int idx4 = w * (FEAT_ / 4) + q;
        float thr = c_nu[k] * d[row];
        float4* V4 = (float4*)V;
        float4 y;
        if (FIRST) {
            y = make_float4(0.f, 0.f, 0.f, 0.f);
        } else {
            float4 vp = V4[idx4];            // v_{t-1}
            y.x = acc.x + vp.x; y.y = acc.y + vp.y;
            y.z = acc.z + vp.z; y.w = acc.w + vp.w;
        }
        float4 o;
        o.x = y.x - softf(acc.x + y.x, thr);
        o.y = y.y - softf(acc.y + y.y, thr);
        o.z = y.z - softf(acc.z + y.z, thr);
        o.w = y.w - softf(acc.w + y.w, thr);
        V4[idx4] = o;                        // v_t
    }
}

// wave per row: acc = sum_k (W_k @ v_k)[row]; U = (dm*F - acc)/(dm+1)
__global__ __launch_bounds__(BLK) void wtv_u_kernel(
    const int* __restrict__ offs, const int* __restrict__ ccol,
    const float* __restrict__ cval, const float* __restrict__ V,
    const float* __restrict__ F, const float* __restrict__ dm,
    float* __restrict__ U) {
    int w    = (blockIdx.x * BLK + threadIdx.x) >> 6;  // row
    int lane = threadIdx.x & 63;
    int sub  = lane >> 4, q = lane & 15;
    if (w >= N_) return;
    float4 acc = {0.f, 0.f, 0.f, 0.f};
    #pragma unroll
    for (int k = 0; k < K_; ++k) {
        int rw  = k * N_ + w;
        int beg = __builtin_amdgcn_readfirstlane(offs[rw]);
        int end = __builtin_amdgcn_readfirstlane(offs[rw + 1]);
        row_accum(ccol, cval, (const float4*)(V + (size_t)k * NF),
                  beg, end, lane, sub, q, acc);
    }
    butterfly4(acc);
    if (sub == 0) {
        int idx4 = w * (FEAT_ / 4) + q;
        float dmv = dm[w];
        float r = 1.0f / (dmv + 1.0f);
        float4 f = ((const float4*)F)[idx4];
        float4 o;
        o.x = (dmv * f.x - acc.x) * r; o.y = (dmv * f.y - acc.y) * r;
        o.z = (dmv * f.z - acc.z) * r; o.w = (dmv * f.w - acc.w) * r;
        ((float4*)U)[idx4] = o;
    }
}

extern "C" void kernel_launch(void* const* d_in, const int* in_sizes, int n_in,
                              void* d_out, int out_size, void* d_ws, size_t ws_size,
                              hipStream_t stream) {
    const float* F      = (const float*)d_in[0];
    const int*   w_rows = (const int*)d_in[1];
    const int*   w_cols = (const int*)d_in[2];
    const float* w_vals = (const float*)d_in[3];
    const float* d      = (const float*)d_in[4];
    const float* mask   = (const float*)d_in[5];
    float* U = (float*)d_out;

    // workspace layout (~38 MB)
    float* V      = (float*)d_ws;                 // 5,120,000 f
    float* dm     = V + (size_t)NF * K_;          // N
    int*   cnt    = (int*)(dm + N_);              // KN
    int*   loc    = cnt + KN;                     // KN
    int*   bsum   = loc + KN;                     // pad 512
    int*   offs   = bsum + 512;                   // KN+1
    int*   cursor = offs + KN + 1;                // KN
    int*   perm   = cursor + KN;                  // NEDGE
    int*   ccol   = perm + NEDGE;                 // NEDGE
    float* cval   = (float*)(ccol + NEDGE);       // NEDGE

    const int gEdge = NEDGE / BLK;                // 5000
    const int gKNw  = (KN * 64) / BLK;            // 20000 (wave per csr row)
    const int gNw   = (N_ * 64) / BLK;            // 5000  (wave per node row)
    const int gN    = (N_ + BLK - 1) / BLK;

    // ---- CSR build ----
    hipMemsetAsync(cnt, 0, (size_t)KN * 4, stream);
    precompute_kernel<<<gN, BLK, 0, stream>>>(d, mask, dm);
    hist_kernel<<<gEdge, BLK, 0, stream>>>(w_rows, cnt);
    scan1_kernel<<<NSB, 256, 0, stream>>>(cnt, loc, bsum);
    scan2_kernel<<<1, 512, 0, stream>>>(bsum);
    scan3_kernel<<<NSB, 256, 0, stream>>>(loc, bsum, offs, cursor);
    scatter_perm_kernel<<<gEdge, BLK, 0, stream>>>(w_rows, cursor, perm);
    build_kernel<<<gEdge, BLK, 0, stream>>>(perm, w_cols, w_vals, ccol, cval);

    // ---- iterations ----
    spmm_fused_kernel<true><<<gKNw, BLK, 0, stream>>>(offs, ccol, cval, F, d, V);
    for (int it = 0; it < NITER; ++it) {
        wtv_u_kernel<<<gNw, BLK, 0, stream>>>(offs, ccol, cval, V, F, dm, U);
        if (it < NITER - 1)
            spmm_fused_kernel<false><<<gKNw, BLK, 0, stream>>>(offs, ccol, cval,
                                                               U, d, V);
    }
}